// Round 8
// baseline (1587.373 us; speedup 1.0000x reference)
//
#include <hip/hip_runtime.h>
#include <math.h>

namespace {

constexpr int BSZ  = 1024;
constexpr int P    = 128;
constexpr int HG   = 128;
constexpr int NH   = 4;
constexpr int N    = 168;     // P + IND
constexpr int NPAD = 176;     // padded token count (11 tiles of 16)

typedef short bf16x8 __attribute__((ext_vector_type(8)));
typedef float f32x4  __attribute__((ext_vector_type(4)));

__device__ __forceinline__ unsigned short f2bf(float x){
  union { float f; unsigned u; } v; v.f = x;
  unsigned r = (v.u + 0x7FFF + ((v.u >> 16) & 1)) >> 16;
  return (unsigned short)r;
}
__device__ __forceinline__ float bf2f(unsigned short b){
  union { unsigned u; float f; } v; v.u = ((unsigned)b) << 16;
  return v.f;
}

// fast asin (A&S 4.4.46, |err|<=2e-8), input already clipped inside (-1,1)
__device__ __forceinline__ float fast_asin(float x){
  float ax = fabsf(x);
  float s = sqrtf(1.f - ax);
  float p = -0.0012624911f;
  p = fmaf(p, ax, 0.0066700901f);
  p = fmaf(p, ax, -0.0170881256f);
  p = fmaf(p, ax, 0.0308918810f);
  p = fmaf(p, ax, -0.0501743046f);
  p = fmaf(p, ax, 0.0889789874f);
  p = fmaf(p, ax, -0.2145988016f);
  p = fmaf(p, ax, 1.5707963050f);
  float r = 1.5707963268f - s * p;
  return copysignf(r, x);
}
// fast atan (odd minimax on [0,1] + reciprocal reduction, |err|~1e-7)
__device__ __forceinline__ float fast_atan(float x){
  float ax = fabsf(x);
  bool inv = ax > 1.f;
  float t = inv ? (1.f / ax) : ax;
  float t2 = t * t;
  float p = -0.01172120f;
  p = fmaf(p, t2, 0.05265332f);
  p = fmaf(p, t2, -0.11643287f);
  p = fmaf(p, t2, 0.19354346f);
  p = fmaf(p, t2, -0.33262347f);
  p = fmaf(p, t2, 0.99997726f);
  float r = t * p;
  if (inv) r = 1.5707963268f - r;
  return copysignf(r, x);
}

// ---------- wave (64-lane) butterfly reductions: result in ALL lanes ----------
__device__ __forceinline__ float wsum(float v){
  #pragma unroll
  for (int o = 1; o < 64; o <<= 1) v += __shfl_xor(v, o, 64);
  return v;
}
__device__ __forceinline__ float wmax(float v){
  #pragma unroll
  for (int o = 1; o < 64; o <<= 1) v = fmaxf(v, __shfl_xor(v, o, 64));
  return v;
}
__device__ __forceinline__ float wmin(float v){
  #pragma unroll
  for (int o = 1; o < 64; o <<= 1) v = fminf(v, __shfl_xor(v, o, 64));
  return v;
}
__device__ __forceinline__ float rsum256(float v, volatile float* red4){
  #pragma unroll
  for (int o = 32; o > 0; o >>= 1) v += __shfl_down(v, o, 64);
  __syncthreads();
  if ((threadIdx.x & 63) == 0) red4[threadIdx.x >> 6] = v;
  __syncthreads();
  return red4[0] + red4[1] + red4[2] + red4[3];
}

// ---------- K1: per-patch features, one WAVE per patch, no LDS, no barriers ----------
__global__ __launch_bounds__(256) void feat_kernel(const float* __restrict__ X,
                                                   float* __restrict__ Xf){
  const int wave = threadIdx.x >> 6, l = threadIdx.x & 63;
  const int pp = blockIdx.x * 4 + wave;          // patch id
  const float* xp = X + (size_t)pp * 128;
  const float x0 = xp[l];
  const float x1 = xp[l + 64];

  // ---- temporal ----
  float sum   = wsum(x0 + x1);
  float mean  = sum * (1.0f / 128.0f);
  float mx    = wmax(fmaxf(x0, x1));
  float mn    = wmin(fminf(x0, x1));
  float sumsq = wsum(fmaf(x0, x0, x1 * x1));
  float c0 = x0 - mean, c1_ = x1 - mean;
  float c0q = c0 * c0, c1q = c1_ * c1_;
  float m2 = wsum(c0q + c1q);
  float m3 = wsum(c0q * c0 + c1q * c1_);
  float m4 = wsum(c0q * c0q + c1q * c1q);
  float var = m2 * (1.0f / 127.0f);
  float sd  = sqrtf(var);
  float rms = sqrtf(sumsq * (1.0f / 128.0f));
  float ex0 = __expf(x0 - mx), ex1 = __expf(x1 - mx);
  float Z   = wsum(ex0 + ex1);
  float SxE = wsum(fmaf(ex0, x0, ex1 * x1));
  float ent = (mx + __logf(Z)) - SxE / Z;
  const float lo = (float)(-1.0 + 1e-7), hi = (float)(1.0 - 1e-7);
  float a0 = fast_asin(fminf(fmaxf(x0, lo), hi));
  float a1 = fast_asin(fminf(fmaxf(x1, lo), hi));
  float amean = wsum(a0 + a1) * (1.0f / 128.0f);
  float ad0 = a0 - amean, ad1 = a1 - amean;
  float std_asin = sqrtf(wsum(fmaf(ad0, ad0, ad1 * ad1)) * (1.0f / 127.0f));
  float b0 = fast_atan(x0), b1v = fast_atan(x1);
  float bmean = wsum(b0 + b1v) * (1.0f / 128.0f);
  float bd0 = b0 - bmean, bd1 = b1v - bmean;
  float std_atan = sqrtf(wsum(fmaf(bd0, bd0, bd1 * bd1)) * (1.0f / 127.0f));
  float kurt = (m4 * (1.0f / 128.0f)) / (sd * sd * sd * sd) - 3.0f;
  float skew = (m3 * (1.0f / 128.0f)) / (sd * sd * sd);

  // ---- DFT: lane l computes bin l via rotation recurrence (64 folded steps) ----
  const float sign = (l & 1) ? -1.0f : 1.0f;
  float sC, cC;
  __sincosf((float)l * 0.049087385212340517f, &sC, &cC);   // 2*pi*l/128
  const float c1r = cC, s1r = -sC;
  const int x0i = __float_as_int(x0), x1i = __float_as_int(x1);
  float re = 0.f, im = 0.f;
  float wc = 1.f, ws = 0.f;
  #pragma unroll 8
  for (int tt = 0; tt < 32; ++tt){
    float s0v = __int_as_float(__builtin_amdgcn_readlane(x0i, tt));
    float s1v = __int_as_float(__builtin_amdgcn_readlane(x1i, tt));
    float se = fmaf(sign, s1v, s0v);
    re = fmaf(se, wc, re);
    im = fmaf(se, ws, im);
    float t1 = ws * s1r, t2 = ws * c1r;
    float nwc = fmaf(wc, c1r, -t1);
    ws = fmaf(wc, s1r, t2);
    wc = nwc;
  }
  { // exact reseed at tt=32: w = e^{-i*pi*l/2}
    int lm = l & 3;
    wc = (lm == 0) ? 1.f : (lm == 2) ? -1.f : 0.f;
    ws = (lm == 1) ? -1.f : (lm == 3) ? 1.f : 0.f;
  }
  #pragma unroll 8
  for (int tt = 32; tt < 64; ++tt){
    float s0v = __int_as_float(__builtin_amdgcn_readlane(x0i, tt));
    float s1v = __int_as_float(__builtin_amdgcn_readlane(x1i, tt));
    float se = fmaf(sign, s1v, s0v);
    re = fmaf(se, wc, re);
    im = fmaf(se, ws, im);
    float t1 = ws * s1r, t2 = ws * c1r;
    float nwc = fmaf(wc, c1r, -t1);
    ws = fmaf(wc, s1r, t2);
    wc = nwc;
  }
  float psd = fmaf(re, re, im * im) * 0.0078125f;          // bins 0..63 (lane l)
  float re64 = wsum(sign * (x0 + x1));                     // bin 64
  float psd64 = re64 * re64 * 0.0078125f;

  const float mult = (l == 0) ? 1.f : 2.f;
  float psum = wsum(psd * mult) + psd64;
  float p2   = wsum(psd * psd * mult) + psd64 * psd64;
  float vm   = wmax(psd);
  float maxp = fmaxf(vm, psd64);
  float meanfreq = (-0.5f * psd64) / psum;
  float pbw = sqrtf(p2 / psum);
  float cand = (psd == vm) ? (float)l : 1e9f;              // first-index argmax
  float lminf = wmin(cand);
  float fmaxv = (psd64 > vm) ? -0.5f : lminf * (1.0f / 128.0f);
  float maxamp = sqrtf(maxp * 128.0f);

  // ---- median (stable rank 64 of 128, multiplicity-aware ballot rank) ----
  float med = -0.5f;
  for (int kt = 0; kt < 64; ++kt){
    float vt = __int_as_float(__builtin_amdgcn_readlane(__float_as_int(psd), kt));
    unsigned long long mask = __ballot(psd < vt);
    int less = 2 * __popcll(mask) - (int)(mask & 1ull) + ((psd64 < vt) ? 1 : 0);
    if (less == 64) med = (float)kt * (1.0f / 128.0f);
    else if (less == 63 && kt >= 1) med = -(float)kt * (1.0f / 128.0f);
  }
  {
    unsigned long long mask = __ballot(psd < psd64);
    int less = 2 * __popcll(mask) - (int)(mask & 1ull);
    if (less == 64) med = -0.5f;
  }

  if (l == 0){
    float* o = Xf + (size_t)pp * 40;
    o[0]  = mx;  o[1]  = mn;  o[2]  = sd;   o[3]  = rms; o[4]  = mean;
    o[5]  = mx - mn;  o[6] = var;  o[7] = ent; o[8] = std_asin; o[9] = std_atan;
    o[10] = kurt; o[11] = skew;
    o[12] = meanfreq;
    o[13] = med;
    o[14] = psum;
    o[15] = 1.0f;
    o[16] = pbw;
    o[17] = maxp;
    o[18] = maxamp;
    o[19] = fmaxv;
  }
}

// ---------- K2: cumsum feature + per-sample normalization ----------
__global__ __launch_bounds__(256) void cumnorm_kernel(float* __restrict__ Xf){
  const int b = blockIdx.x, t = threadIdx.x;
  __shared__ float arr[128 * 40];
  __shared__ float red4[4];
  float* base = Xf + b * 5120;
  for (int idx = t; idx < 128 * 20; idx += 256){
    int p = idx / 20, c = idx - p * 20;
    arr[p * 40 + c] = base[p * 40 + c];
  }
  __syncthreads();
  if (t < 20){
    float acc = 0.f;
    for (int p = 0; p < 128; ++p){
      acc += arr[p * 40 + t];
      arr[p * 40 + 20 + t] = acc / sqrtf(fmaxf(fabsf(acc), 1e-12f));
    }
  }
  __syncthreads();
  float pa = 0.f;
  for (int idx = t; idx < 5120; idx += 256){ float v = arr[idx]; pa = fmaf(v, v, pa); }
  float nrm = sqrtf(rsum256(pa, red4));
  for (int idx = t; idx < 5120; idx += 256) base[idx] = arr[idx] / nrm;
}

// ---------- K3: A_t (register-tiled fp32) ----------
__global__ __launch_bounds__(256) void adjt_kernel(const float* __restrict__ Xf,
    const float* __restrict__ w1, const float* __restrict__ b1,
    const float* __restrict__ w2, const float* __restrict__ b2,
    float* __restrict__ At){
  const int b = blockIdx.x, t = threadIdx.x;
  __shared__ float xf[5120];          // stride 40
  __shared__ float T[128 * 64];
  const float* src = Xf + b * 5120;
  for (int idx = t; idx < 1280; idx += 256)
    *((float4*)xf + idx) = *((const float4*)src + idx);
  __syncthreads();
  {
    const int k0 = (t & 15) * 4, i0 = (t >> 4) * 8;
    float4 bv = *(const float4*)&b1[k0];
    float acc[8][4];
    #pragma unroll
    for (int di = 0; di < 8; ++di){ acc[di][0]=bv.x; acc[di][1]=bv.y; acc[di][2]=bv.z; acc[di][3]=bv.w; }
    for (int c = 0; c < 40; ++c){
      float4 wv = *(const float4*)&w1[c * 64 + k0];
      #pragma unroll
      for (int di = 0; di < 8; ++di){
        float xv = xf[(i0 + di) * 40 + c];
        acc[di][0] = fmaf(xv, wv.x, acc[di][0]);
        acc[di][1] = fmaf(xv, wv.y, acc[di][1]);
        acc[di][2] = fmaf(xv, wv.z, acc[di][2]);
        acc[di][3] = fmaf(xv, wv.w, acc[di][3]);
      }
    }
    #pragma unroll
    for (int di = 0; di < 8; ++di){
      float4 o;
      o.x = tanhf(acc[di][0]); o.y = tanhf(acc[di][1]);
      o.z = tanhf(acc[di][2]); o.w = tanhf(acc[di][3]);
      *(float4*)&T[(i0 + di) * 64 + k0] = o;
    }
  }
  __syncthreads();
  {
    const int j0 = (t & 31) * 4, i0 = (t >> 5) * 16;
    float4 bv = *(const float4*)&b2[j0];
    float acc[16][4];
    #pragma unroll
    for (int di = 0; di < 16; ++di){ acc[di][0]=bv.x; acc[di][1]=bv.y; acc[di][2]=bv.z; acc[di][3]=bv.w; }
    for (int k = 0; k < 64; ++k){
      float4 wv = *(const float4*)&w2[k * 128 + j0];
      #pragma unroll
      for (int di = 0; di < 16; ++di){
        float tv = T[(i0 + di) * 64 + k];
        acc[di][0] = fmaf(tv, wv.x, acc[di][0]);
        acc[di][1] = fmaf(tv, wv.y, acc[di][1]);
        acc[di][2] = fmaf(tv, wv.z, acc[di][2]);
        acc[di][3] = fmaf(tv, wv.w, acc[di][3]);
      }
    }
    float* dst = At + (size_t)b * 16384;
    #pragma unroll
    for (int di = 0; di < 16; ++di)
      *(float4*)&dst[(i0 + di) * 128 + j0] = *(float4*)acc[di];
  }
}

// ---------- K4: A_s ----------
__global__ __launch_bounds__(256) void adjs_kernel(const float* __restrict__ Xf,
    const float* __restrict__ w1, const float* __restrict__ b1,
    const float* __restrict__ w2, const float* __restrict__ b2,
    float* __restrict__ As){
  const int b = blockIdx.x, t = threadIdx.x;
  __shared__ float xf[5120];
  __shared__ float T2[40 * 64];
  const float* src = Xf + b * 5120;
  for (int idx = t; idx < 1280; idx += 256)
    *((float4*)xf + idx) = *((const float4*)src + idx);
  __syncthreads();
  for (int idx = t; idx < 40 * 64; idx += 256){
    int i = idx >> 6, k = idx & 63;
    float acc = b1[k];
    for (int p = 0; p < 128; ++p) acc = fmaf(xf[p * 40 + i], w1[p * 64 + k], acc);
    T2[idx] = tanhf(acc);
  }
  __syncthreads();
  float* dst = As + b * 1600;
  for (int idx = t; idx < 1600; idx += 256){
    int i = idx / 40, j = idx - i * 40;
    float acc = b2[j];
    #pragma unroll 8
    for (int k = 0; k < 64; ++k) acc = fmaf(T2[i * 64 + k], w2[k * 40 + j], acc);
    dst[idx] = acc;
  }
}

// ---------- K5: H_s (register-tiled) ----------
__global__ __launch_bounds__(256) void hs_kernel(const float* __restrict__ Xf,
    const float* __restrict__ As_g, const float* __restrict__ w, const float* __restrict__ bias,
    float* __restrict__ H){
  const int b = blockIdx.x, t = threadIdx.x;
  __shared__ float xf[5120];          // stride 40
  __shared__ float As[1600];
  __shared__ float M[40 * 128];
  const float* src = Xf + b * 5120;
  for (int idx = t; idx < 1280; idx += 256)
    *((float4*)xf + idx) = *((const float4*)src + idx);
  for (int idx = t; idx < 400; idx += 256)
    *((float4*)As + idx) = *((const float4*)(As_g + b * 1600) + idx);
  __syncthreads();
  {
    const int p0 = (t & 31) * 4, i0 = (t >> 5) * 5;
    float acc[5][4];
    #pragma unroll
    for (int di = 0; di < 5; ++di)
      #pragma unroll
      for (int dp = 0; dp < 4; ++dp) acc[di][dp] = 0.f;
    for (int m = 0; m < 40; m += 4){
      float4 a4[5], x4[4];
      #pragma unroll
      for (int di = 0; di < 5; ++di) a4[di] = *(const float4*)&As[(i0 + di) * 40 + m];
      #pragma unroll
      for (int dp = 0; dp < 4; ++dp) x4[dp] = *(const float4*)&xf[(p0 + dp) * 40 + m];
      #pragma unroll
      for (int dm = 0; dm < 4; ++dm)
        #pragma unroll
        for (int di = 0; di < 5; ++di){
          float av = (&a4[di].x)[dm];
          #pragma unroll
          for (int dp = 0; dp < 4; ++dp)
            acc[di][dp] = fmaf(av, (&x4[dp].x)[dm], acc[di][dp]);
        }
    }
    #pragma unroll
    for (int di = 0; di < 5; ++di)
      *(float4*)&M[(i0 + di) * 128 + p0] = *(float4*)acc[di];
  }
  __syncthreads();
  {
    const int j0 = (t & 31) * 4, i0 = (t >> 5) * 5;
    float4 bv = *(const float4*)&bias[j0];
    float acc[5][4];
    #pragma unroll
    for (int di = 0; di < 5; ++di){ acc[di][0]=bv.x; acc[di][1]=bv.y; acc[di][2]=bv.z; acc[di][3]=bv.w; }
    for (int p = 0; p < 128; ++p){
      float4 wv = *(const float4*)&w[p * 128 + j0];
      #pragma unroll
      for (int di = 0; di < 5; ++di){
        float mv = M[(i0 + di) * 128 + p];
        acc[di][0] = fmaf(mv, wv.x, acc[di][0]);
        acc[di][1] = fmaf(mv, wv.y, acc[di][1]);
        acc[di][2] = fmaf(mv, wv.z, acc[di][2]);
        acc[di][3] = fmaf(mv, wv.w, acc[di][3]);
      }
    }
    float* dst = H + (size_t)b * (N * HG);
    #pragma unroll
    for (int di = 0; di < 5; ++di){
      float4 o;
      o.x = (acc[di][0] >= 0.f) ? acc[di][0] : 0.01f * acc[di][0];
      o.y = (acc[di][1] >= 0.f) ? acc[di][1] : 0.01f * acc[di][1];
      o.z = (acc[di][2] >= 0.f) ? acc[di][2] : 0.01f * acc[di][2];
      o.w = (acc[di][3] >= 0.f) ? acc[di][3] : 0.01f * acc[di][3];
      *(float4*)&dst[(i0 + di) * 128 + j0] = o;
    }
  }
}

// ---------- K6: H_t (register-tiled) ----------
__global__ __launch_bounds__(256) void ht_kernel(const float* __restrict__ Xf,
    const float* __restrict__ At_g, const float* __restrict__ w, const float* __restrict__ bias,
    float* __restrict__ H){
  const int b = blockIdx.x, t = threadIdx.x;
  __shared__ float xf[5120];          // stride 40
  __shared__ float M2[128 * 40];
  const float* src = Xf + b * 5120;
  for (int idx = t; idx < 1280; idx += 256)
    *((float4*)xf + idx) = *((const float4*)src + idx);
  __syncthreads();
  {
    const int c0 = (t & 7) * 5, i0 = (t >> 3) * 4;
    const float* At = At_g + (size_t)b * 16384;
    float acc[4][5];
    #pragma unroll
    for (int di = 0; di < 4; ++di)
      #pragma unroll
      for (int dc = 0; dc < 5; ++dc) acc[di][dc] = 0.f;
    for (int m = 0; m < 128; m += 4){
      float4 a4[4];
      #pragma unroll
      for (int di = 0; di < 4; ++di) a4[di] = *(const float4*)&At[(i0 + di) * 128 + m];
      #pragma unroll
      for (int dm = 0; dm < 4; ++dm){
        float xv[5];
        #pragma unroll
        for (int dc = 0; dc < 5; ++dc) xv[dc] = xf[(m + dm) * 40 + c0 + dc];
        #pragma unroll
        for (int di = 0; di < 4; ++di){
          float av = (&a4[di].x)[dm];
          #pragma unroll
          for (int dc = 0; dc < 5; ++dc)
            acc[di][dc] = fmaf(av, xv[dc], acc[di][dc]);
        }
      }
    }
    #pragma unroll
    for (int di = 0; di < 4; ++di)
      #pragma unroll
      for (int dc = 0; dc < 5; ++dc)
        M2[(i0 + di) * 40 + c0 + dc] = acc[di][dc];
  }
  __syncthreads();
  {
    const int j0 = (t & 31) * 4, i0 = (t >> 5) * 16;
    float4 bv = *(const float4*)&bias[j0];
    float acc[16][4];
    #pragma unroll
    for (int di = 0; di < 16; ++di){ acc[di][0]=bv.x; acc[di][1]=bv.y; acc[di][2]=bv.z; acc[di][3]=bv.w; }
    for (int c = 0; c < 40; ++c){
      float4 wv = *(const float4*)&w[c * 128 + j0];
      #pragma unroll
      for (int di = 0; di < 16; ++di){
        float mv = M2[(i0 + di) * 40 + c];
        acc[di][0] = fmaf(mv, wv.x, acc[di][0]);
        acc[di][1] = fmaf(mv, wv.y, acc[di][1]);
        acc[di][2] = fmaf(mv, wv.z, acc[di][2]);
        acc[di][3] = fmaf(mv, wv.w, acc[di][3]);
      }
    }
    float* dst = H + (size_t)b * (N * HG) + 40 * 128;
    #pragma unroll
    for (int di = 0; di < 16; ++di){
      float4 o;
      o.x = (acc[di][0] >= 0.f) ? acc[di][0] : 0.01f * acc[di][0];
      o.y = (acc[di][1] >= 0.f) ? acc[di][1] : 0.01f * acc[di][1];
      o.z = (acc[di][2] >= 0.f) ? acc[di][2] : 0.01f * acc[di][2];
      o.w = (acc[di][3] >= 0.f) ? acc[di][3] : 0.01f * acc[di][3];
      *(float4*)&dst[(i0 + di) * 128 + j0] = o;
    }
  }
}

// ---------- init out: fc_b + sum(vb x fcw) folded constant (softmax rows sum to 1) ----------
__global__ __launch_bounds__(256) void initout_kernel(float* __restrict__ out,
    const float* __restrict__ fcb, const float* __restrict__ fcw,
    const float* __restrict__ vb){
  __shared__ float red4[4];
  float p = 0.f;
  for (int k = threadIdx.x; k < 86016; k += 256)
    p = fmaf(fcw[k], vb[k & 511], p);
  float tot = rsum256(p, red4);
  float v = fcb[0] + tot;
  for (int i = threadIdx.x; i < BSZ; i += 256) out[i] = v;
}

// ---------- prep: per-head M^T, Wv^T, c1/c2/c3; sliced over 8 blocks/head ----------
__global__ __launch_bounds__(256) void prep_kernel(
    const float* __restrict__ qw, const float* __restrict__ qb,
    const float* __restrict__ kw, const float* __restrict__ kb,
    const float* __restrict__ vw,
    short* __restrict__ MT, short* __restrict__ WvT,
    float* __restrict__ c1, float* __restrict__ c2, float* __restrict__ c3){
  const int h = blockIdx.x, sl = blockIdx.y, t = threadIdx.x;
  const float* Q = qw + h * 16384;
  const float* K = kw + h * 16384;
  const float* V = vw + h * 16384;
  for (int idx = t; idx < 2048; idx += 256){
    int j = sl * 16 + (idx >> 7), d = idx & 127;
    float acc = 0.f;
    for (int e = 0; e < 128; ++e) acc = fmaf(Q[d * 128 + e], K[j * 128 + e], acc);
    MT[h * 16384 + j * 128 + d] = (short)f2bf(acc);     // MT[j][d] = M[d][j]
  }
  for (int idx = t; idx < 2048; idx += 256){
    int e = sl * 16 + (idx >> 7), d = idx & 127;
    WvT[h * 16384 + e * 128 + d] = (short)f2bf(V[d * 128 + e]);
  }
  if (t < 16){
    int r = sl * 16 + t;
    float a = 0.f, bsum = 0.f;
    for (int e = 0; e < 128; ++e){
      a    = fmaf(Q[r * 128 + e], kb[h * 128 + e], a);
      bsum = fmaf(K[r * 128 + e], qb[h * 128 + e], bsum);
    }
    c1[h * 128 + r] = a;
    c2[h * 128 + r] = bsum;
  }
  if (t == 16 && sl == 0){
    float a = 0.f;
    for (int e = 0; e < 128; ++e) a = fmaf(qb[h * 128 + e], kb[h * 128 + e], a);
    c3[h] = a;
  }
}

// ---------- cast H -> bf16 with zero-padded rows 168..175 ----------
__global__ __launch_bounds__(256) void cast_kernel(const float* __restrict__ H,
                                                   short* __restrict__ Hbf){
  const int b = blockIdx.x;
  for (int idx = threadIdx.x; idx < NPAD * 128; idx += 256){
    int n = idx >> 7, d = idx & 127;
    float v = (n < N) ? H[((size_t)b * N + n) * 128 + d] : 0.f;
    Hbf[(size_t)b * NPAD * 128 + idx] = (short)f2bf(v);
  }
}

// ---------- u1/u2 precompute: u1[n]=H[n]·c1, u2[n]=H[n]·c2 per (b,h) ----------
__global__ __launch_bounds__(256) void uprep_kernel(const short* __restrict__ Hbf,
    const float* __restrict__ c1, const float* __restrict__ c2,
    float* __restrict__ u1g, float* __restrict__ u2g){
  const int b = blockIdx.x, t = threadIdx.x;
  for (int idx = t; idx < 176 * 4; idx += 256){
    int n = idx >> 2, h = idx & 3;
    const bf16x8* rp = (const bf16x8*)(Hbf + (size_t)b * NPAD * 128 + (size_t)n * 128);
    const float* C1 = c1 + h * 128;
    const float* C2 = c2 + h * 128;
    float a1 = 0.f, a2 = 0.f;
    for (int kk = 0; kk < 16; ++kk){
      bf16x8 v = rp[kk];
      #pragma unroll
      for (int j = 0; j < 8; ++j){
        float hv = bf2f((unsigned short)v[j]);
        a1 = fmaf(hv, C1[kk * 8 + j], a1);
        a2 = fmaf(hv, C2[kk * 8 + j], a2);
      }
    }
    u1g[(size_t)(b * 4 + h) * 176 + n] = a1;
    u2g[(size_t)(b * 4 + h) * 176 + n] = a2;
  }
}

// ---------- fused attention: XCD-swizzled 1-D grid; one block per (b,h) ----------
__global__ __launch_bounds__(256, 4) void attn_fused(
    const short* __restrict__ Hbf, const short* __restrict__ MT,
    const short* __restrict__ WvT,
    const float* __restrict__ u1g, const float* __restrict__ u2g,
    const float* __restrict__ c3g, const float* __restrict__ fcw,
    float* __restrict__ out){
  // XCD-aware swizzle: blocks dispatch round-robin over 8 XCDs (id & 7).
  // Give each XCD a contiguous 128-sample range -> Hbf working set per
  // XCD-L2 is ~32 samples x 45 KB at a time instead of all 46 MB.
  const int id = blockIdx.x;
  const int xcd = id & 7, slot = id >> 3;
  const int b = xcd * 128 + (slot >> 2);
  const int h = slot & 3;
  const int t = threadIdx.x;
  const int w = t >> 6, l = t & 63, quad = l >> 4, l15 = l & 15;

  __shared__ __align__(16) short Tsh[48 * 128];     // T (XOR-swizzled), per z
  __shared__ __align__(16) short U[4 * 16 * 200];   // phase W scratch, then Ssh (48x184)
  __shared__ float u1f[176];
  __shared__ float u2f[176];
  __shared__ float red4[4];

  const short* Hb   = Hbf + (size_t)b * NPAD * 128;
  const short* MTh  = MT + h * 16384;
  const short* WvTh = WvT + h * 16384;
  const float c3v = c3g[h];
  const float inv = 0.08838834764831845f;   // 1/sqrt(128)

  if (t < 176){
    u1f[t] = u1g[(size_t)(b * 4 + h) * 176 + t];
    u2f[t] = u2g[(size_t)(b * 4 + h) * 176 + t];
  }

  // ---- Phase W: HWvT B-fragments -> registers (per-wave scratch, no barrier) ----
  bf16x8 W2f[2][6];
  {
    short* sc = &U[w * 3200];          // 16 x 200 per wave
    for (int ei = 0; ei < 2; ++ei){
      const int et = w * 2 + ei;
      bf16x8 A[4];
      #pragma unroll
      for (int kk = 0; kk < 4; ++kk)
        A[kk] = *(const bf16x8*)(WvTh + (size_t)(et * 16 + l15) * 128 + kk * 32 + quad * 8);
      for (int mt = 0; mt < 11; ++mt){
        f32x4 acc = {0.f, 0.f, 0.f, 0.f};
        #pragma unroll
        for (int kk = 0; kk < 4; ++kk){
          bf16x8 B = *(const bf16x8*)(Hb + (size_t)(mt * 16 + l15) * 128 + kk * 32 + quad * 8);
          acc = __builtin_amdgcn_mfma_f32_16x16x32_bf16(A[kk], B, acc, 0, 0, 0);
        }
        #pragma unroll
        for (int r = 0; r < 4; ++r)
          sc[(quad * 4 + r) * 200 + mt * 16 + l15] = (short)f2bf(acc[r]);
      }
      { // zero cols 176..191 (16 rows x 16 cols, one 8B write per lane)
        int row = l >> 2, co = 176 + (l & 3) * 4;
        *(unsigned long long*)(&sc[row * 200 + co]) = 0ull;
      }
      #pragma unroll
      for (int kt = 0; kt < 6; ++kt)
        W2f[ei][kt] = *(const bf16x8*)(&sc[l15 * 200 + kt * 32 + quad * 8]);
    }
  }
  __syncthreads();    // scratch dead; u1f/u2f visible

  float tp = 0.f;
  short* Ssh = U;     // 48 rows, stride 184
  for (int z = 0; z < 4; ++z){
    const int NT = (z < 3) ? 3 : 2;
    const int rowbase = z * 48;

    // ---- Phase A: T = H_rows @ M (write bf16, XOR-swizzled) ----
    for (int jt = 0; jt < 2; ++jt){
      const int j0 = (w * 2 + jt) * 16;
      bf16x8 B[4];
      #pragma unroll
      for (int kk = 0; kk < 4; ++kk)
        B[kk] = *(const bf16x8*)(MTh + (j0 + l15) * 128 + kk * 32 + quad * 8);
      for (int nt = 0; nt < NT; ++nt){
        f32x4 acc = {0.f, 0.f, 0.f, 0.f};
        #pragma unroll
        for (int kk = 0; kk < 4; ++kk){
          bf16x8 A = *(const bf16x8*)(Hb + (size_t)(rowbase + nt * 16 + l15) * 128 + kk * 32 + quad * 8);
          acc = __builtin_amdgcn_mfma_f32_16x16x32_bf16(A, B[kk], acc, 0, 0, 0);
        }
        const int jcol = j0 + l15, ch = jcol >> 3;
        #pragma unroll
        for (int r = 0; r < 4; ++r){
          int row = nt * 16 + quad * 4 + r;
          Tsh[row * 128 + ((ch ^ (row & 15)) << 3) + (jcol & 7)] = (short)f2bf(acc[r]);
        }
      }
    }
    __syncthreads();

    // ---- Phase S: S = T @ H^T (+rank-1 terms), bf16 into Ssh ----
    for (int mi = 0; mi < 3; ++mi){
      const int mt = w + mi * 4;
      if (mt >= 11) break;
      const int m0 = mt * 16;
      bf16x8 B[4];
      #pragma unroll
      for (int kk = 0; kk < 4; ++kk)
        B[kk] = *(const bf16x8*)(Hb + (size_t)(m0 + l15) * 128 + kk * 32 + quad * 8);
      const int m = m0 + l15;
      const float u2v = u2f[m];
      for (int nt = 0; nt < NT; ++nt){
        f32x4 acc = {0.f, 0.f, 0.f, 0.f};
        #pragma unroll
        for (int kk = 0; kk < 4; ++kk){
          int row = nt * 16 + l15;
          bf16x8 A = *(const bf16x8*)(&Tsh[row * 128 + (((kk * 4 + quad) ^ l15) << 3)]);
          acc = __builtin_amdgcn_mfma_f32_16x16x32_bf16(A, B[kk], acc, 0, 0, 0);
        }
        #pragma unroll
        for (int r = 0; r < 4; ++r){
          int nl = nt * 16 + quad * 4 + r;
          float s = (acc[r] + u1f[rowbase + nl] + u2v + c3v) * inv;
          Ssh[nl * 184 + m] = (short)f2bf(s);
        }
      }
    }
    __syncthreads();

    // ---- softmax: one row per wave pass; cols 0..167 valid, 168..183 -> 0 ----
    {
      const int nrw = NT * 4;
      for (int rr = 0; rr < nrw; ++rr){
        const int r = w * nrw + rr;
        short* rowp = &Ssh[r * 184];
        float v0 = bf2f((unsigned short)rowp[l]);
        float v1 = bf2f((unsigned short)rowp[64 + l]);
        float v2 = (l < 40) ? bf2f((unsigned short)rowp[128 + l]) : -1e30f;
        float mv = wmax(fmaxf(fmaxf(v0, v1), v2));
        float e0 = __expf(v0 - mv);
        float e1 = __expf(v1 - mv);
        float e2 = (l < 40) ? __expf(v2 - mv) : 0.f;
        float sinv = 1.f / wsum(e0 + e1 + e2);
        rowp[l]      = (short)f2bf(e0 * sinv);
        rowp[64 + l] = (short)f2bf(e1 * sinv);
        if (l < 56) rowp[128 + l] = (l < 40) ? (short)f2bf(e2 * sinv) : (short)0;
      }
    }
    __syncthreads();

    // ---- Phase O: O = P @ HWv (B from registers), fused FC reduction ----
    for (int ei = 0; ei < 2; ++ei){
      const int e0 = (w * 2 + ei) * 16;
      for (int nt = 0; nt < NT; ++nt){
        f32x4 acc = {0.f, 0.f, 0.f, 0.f};
        #pragma unroll
        for (int kt = 0; kt < 6; ++kt){
          bf16x8 A = {0, 0, 0, 0, 0, 0, 0, 0};
          if (kt != 5 || quad < 2)
            A = *(const bf16x8*)(&Ssh[(nt * 16 + l15) * 184 + kt * 32 + quad * 8]);
          acc = __builtin_amdgcn_mfma_f32_16x16x32_bf16(A, W2f[ei][kt], acc, 0, 0, 0);
        }
        #pragma unroll
        for (int r = 0; r < 4; ++r){
          int ng = rowbase + nt * 16 + quad * 4 + r;
          if (ng < N)
            tp = fmaf(acc[r], fcw[ng * 512 + h * 128 + e0 + l15], tp);
        }
      }
    }
    __syncthreads();   // protect Tsh/Ssh reuse next z
  }
  float tot = rsum256(tp, red4);
  if (t == 0) atomicAdd(out + b, tot);
}

} // anonymous namespace

extern "C" void kernel_launch(void* const* d_in, const int* in_sizes, int n_in,
                              void* d_out, int out_size, void* d_ws, size_t ws_size,
                              hipStream_t stream) {
  (void)in_sizes; (void)n_in; (void)out_size;
  const float* X      = (const float*)d_in[0];
  const float* spa_w1 = (const float*)d_in[1];
  const float* spa_b1 = (const float*)d_in[2];
  const float* spa_w2 = (const float*)d_in[3];
  const float* spa_b2 = (const float*)d_in[4];
  const float* tem_w1 = (const float*)d_in[5];
  const float* tem_b1 = (const float*)d_in[6];
  const float* tem_w2 = (const float*)d_in[7];
  const float* tem_b2 = (const float*)d_in[8];
  const float* sgnn_w = (const float*)d_in[9];
  const float* sgnn_b = (const float*)d_in[10];
  const float* tgnn_w = (const float*)d_in[11];
  const float* tgnn_b = (const float*)d_in[12];
  const float* q_w    = (const float*)d_in[13];
  const float* q_b    = (const float*)d_in[14];
  const float* k_w    = (const float*)d_in[15];
  const float* k_b    = (const float*)d_in[16];
  const float* v_w    = (const float*)d_in[17];
  const float* v_b    = (const float*)d_in[18];
  const float* fc_w   = (const float*)d_in[19];
  const float* fc_b   = (const float*)d_in[20];
  float* out = (float*)d_out;

  if (ws_size < (size_t)182714368) return;

  char* wsb = (char*)d_ws;
  float* H   = (float*)wsb;
  char*  Rb  = wsb + 88080384;
  float* Xf  = (float*)Rb;
  float* As  = (float*)(Rb + 20971520);
  float* At  = (float*)(Rb + 27525120);
  short* Hbf = (short*)Rb;
  char*  Pb  = Rb + 46137344;
  short* MT  = (short*)Pb;
  short* WvT = (short*)(Pb + 131072);
  float* c1  = (float*)(Pb + 262144);
  float* c2  = (float*)(Pb + 264192);
  float* c3  = (float*)(Pb + 266240);
  float* u1g = (float*)(Pb + 270336);
  float* u2g = (float*)(Pb + 270336 + 2883584);

  feat_kernel<<<BSZ * P / 4, 256, 0, stream>>>(X, Xf);
  cumnorm_kernel<<<BSZ, 256, 0, stream>>>(Xf);
  adjt_kernel<<<BSZ, 256, 0, stream>>>(Xf, tem_w1, tem_b1, tem_w2, tem_b2, At);
  adjs_kernel<<<BSZ, 256, 0, stream>>>(Xf, spa_w1, spa_b1, spa_w2, spa_b2, As);
  hs_kernel<<<BSZ, 256, 0, stream>>>(Xf, As, sgnn_w, sgnn_b, H);
  ht_kernel<<<BSZ, 256, 0, stream>>>(Xf, At, tgnn_w, tgnn_b, H);
  prep_kernel<<<dim3(NH, 8), 256, 0, stream>>>(q_w, q_b, k_w, k_b, v_w, MT, WvT, c1, c2, c3);
  cast_kernel<<<BSZ, 256, 0, stream>>>(H, Hbf);          // H fp32 dead after this
  uprep_kernel<<<BSZ, 256, 0, stream>>>(Hbf, c1, c2, u1g, u2g);
  initout_kernel<<<1, 256, 0, stream>>>(out, fc_b, fc_w, v_b);
  attn_fused<<<NH * BSZ, 256, 0, stream>>>(Hbf, MT, WvT, u1g, u2g, c3, fc_w, out);
}

// Round 9
// 1476.734 us; speedup vs baseline: 1.0749x; 1.0749x over previous
//
#include <hip/hip_runtime.h>
#include <math.h>

namespace {

constexpr int BSZ  = 1024;
constexpr int P    = 128;
constexpr int HG   = 128;
constexpr int NH   = 4;
constexpr int N    = 168;     // P + IND
constexpr int NPAD = 176;     // padded token count (11 tiles of 16)

typedef short bf16x8 __attribute__((ext_vector_type(8)));
typedef float f32x4  __attribute__((ext_vector_type(4)));

__device__ __forceinline__ unsigned short f2bf(float x){
  union { float f; unsigned u; } v; v.f = x;
  unsigned r = (v.u + 0x7FFF + ((v.u >> 16) & 1)) >> 16;
  return (unsigned short)r;
}
__device__ __forceinline__ float bf2f(unsigned short b){
  union { unsigned u; float f; } v; v.u = ((unsigned)b) << 16;
  return v.f;
}

// fast asin (A&S 4.4.46, |err|<=2e-8), input already clipped inside (-1,1)
__device__ __forceinline__ float fast_asin(float x){
  float ax = fabsf(x);
  float s = sqrtf(1.f - ax);
  float p = -0.0012624911f;
  p = fmaf(p, ax, 0.0066700901f);
  p = fmaf(p, ax, -0.0170881256f);
  p = fmaf(p, ax, 0.0308918810f);
  p = fmaf(p, ax, -0.0501743046f);
  p = fmaf(p, ax, 0.0889789874f);
  p = fmaf(p, ax, -0.2145988016f);
  p = fmaf(p, ax, 1.5707963050f);
  float r = 1.5707963268f - s * p;
  return copysignf(r, x);
}
// fast atan (odd minimax on [0,1] + reciprocal reduction, |err|~1e-7)
__device__ __forceinline__ float fast_atan(float x){
  float ax = fabsf(x);
  bool inv = ax > 1.f;
  float t = inv ? (1.f / ax) : ax;
  float t2 = t * t;
  float p = -0.01172120f;
  p = fmaf(p, t2, 0.05265332f);
  p = fmaf(p, t2, -0.11643287f);
  p = fmaf(p, t2, 0.19354346f);
  p = fmaf(p, t2, -0.33262347f);
  p = fmaf(p, t2, 0.99997726f);
  float r = t * p;
  if (inv) r = 1.5707963268f - r;
  return copysignf(r, x);
}

// ---------- wave (64-lane) butterfly reductions: result in ALL lanes ----------
__device__ __forceinline__ float wsum(float v){
  #pragma unroll
  for (int o = 1; o < 64; o <<= 1) v += __shfl_xor(v, o, 64);
  return v;
}
__device__ __forceinline__ float wmax(float v){
  #pragma unroll
  for (int o = 1; o < 64; o <<= 1) v = fmaxf(v, __shfl_xor(v, o, 64));
  return v;
}
__device__ __forceinline__ float wmin(float v){
  #pragma unroll
  for (int o = 1; o < 64; o <<= 1) v = fminf(v, __shfl_xor(v, o, 64));
  return v;
}
__device__ __forceinline__ float rsum256(float v, volatile float* red4){
  #pragma unroll
  for (int o = 32; o > 0; o >>= 1) v += __shfl_down(v, o, 64);
  __syncthreads();
  if ((threadIdx.x & 63) == 0) red4[threadIdx.x >> 6] = v;
  __syncthreads();
  return red4[0] + red4[1] + red4[2] + red4[3];
}

// ---------- K1: per-patch features, one WAVE per patch, no LDS, no barriers ----------
__global__ __launch_bounds__(256) void feat_kernel(const float* __restrict__ X,
                                                   float* __restrict__ Xf){
  const int wave = threadIdx.x >> 6, l = threadIdx.x & 63;
  const int pp = blockIdx.x * 4 + wave;          // patch id
  const float* xp = X + (size_t)pp * 128;
  const float x0 = xp[l];
  const float x1 = xp[l + 64];

  // ---- temporal ----
  float sum   = wsum(x0 + x1);
  float mean  = sum * (1.0f / 128.0f);
  float mx    = wmax(fmaxf(x0, x1));
  float mn    = wmin(fminf(x0, x1));
  float sumsq = wsum(fmaf(x0, x0, x1 * x1));
  float c0 = x0 - mean, c1_ = x1 - mean;
  float c0q = c0 * c0, c1q = c1_ * c1_;
  float m2 = wsum(c0q + c1q);
  float m3 = wsum(c0q * c0 + c1q * c1_);
  float m4 = wsum(c0q * c0q + c1q * c1q);
  float var = m2 * (1.0f / 127.0f);
  float sd  = sqrtf(var);
  float rms = sqrtf(sumsq * (1.0f / 128.0f));
  float ex0 = __expf(x0 - mx), ex1 = __expf(x1 - mx);
  float Z   = wsum(ex0 + ex1);
  float SxE = wsum(fmaf(ex0, x0, ex1 * x1));
  float ent = (mx + __logf(Z)) - SxE / Z;
  const float lo = (float)(-1.0 + 1e-7), hi = (float)(1.0 - 1e-7);
  float a0 = fast_asin(fminf(fmaxf(x0, lo), hi));
  float a1 = fast_asin(fminf(fmaxf(x1, lo), hi));
  float amean = wsum(a0 + a1) * (1.0f / 128.0f);
  float ad0 = a0 - amean, ad1 = a1 - amean;
  float std_asin = sqrtf(wsum(fmaf(ad0, ad0, ad1 * ad1)) * (1.0f / 127.0f));
  float b0 = fast_atan(x0), b1v = fast_atan(x1);
  float bmean = wsum(b0 + b1v) * (1.0f / 128.0f);
  float bd0 = b0 - bmean, bd1 = b1v - bmean;
  float std_atan = sqrtf(wsum(fmaf(bd0, bd0, bd1 * bd1)) * (1.0f / 127.0f));
  float kurt = (m4 * (1.0f / 128.0f)) / (sd * sd * sd * sd) - 3.0f;
  float skew = (m3 * (1.0f / 128.0f)) / (sd * sd * sd);

  // ---- DFT: lane l computes bin l via rotation recurrence (64 folded steps) ----
  const float sign = (l & 1) ? -1.0f : 1.0f;
  float sC, cC;
  __sincosf((float)l * 0.049087385212340517f, &sC, &cC);   // 2*pi*l/128
  const float c1r = cC, s1r = -sC;
  const int x0i = __float_as_int(x0), x1i = __float_as_int(x1);
  float re = 0.f, im = 0.f;
  float wc = 1.f, ws = 0.f;
  #pragma unroll 8
  for (int tt = 0; tt < 32; ++tt){
    float s0v = __int_as_float(__builtin_amdgcn_readlane(x0i, tt));
    float s1v = __int_as_float(__builtin_amdgcn_readlane(x1i, tt));
    float se = fmaf(sign, s1v, s0v);
    re = fmaf(se, wc, re);
    im = fmaf(se, ws, im);
    float t1 = ws * s1r, t2 = ws * c1r;
    float nwc = fmaf(wc, c1r, -t1);
    ws = fmaf(wc, s1r, t2);
    wc = nwc;
  }
  { // exact reseed at tt=32: w = e^{-i*pi*l/2}
    int lm = l & 3;
    wc = (lm == 0) ? 1.f : (lm == 2) ? -1.f : 0.f;
    ws = (lm == 1) ? -1.f : (lm == 3) ? 1.f : 0.f;
  }
  #pragma unroll 8
  for (int tt = 32; tt < 64; ++tt){
    float s0v = __int_as_float(__builtin_amdgcn_readlane(x0i, tt));
    float s1v = __int_as_float(__builtin_amdgcn_readlane(x1i, tt));
    float se = fmaf(sign, s1v, s0v);
    re = fmaf(se, wc, re);
    im = fmaf(se, ws, im);
    float t1 = ws * s1r, t2 = ws * c1r;
    float nwc = fmaf(wc, c1r, -t1);
    ws = fmaf(wc, s1r, t2);
    wc = nwc;
  }
  float psd = fmaf(re, re, im * im) * 0.0078125f;          // bins 0..63 (lane l)
  float re64 = wsum(sign * (x0 + x1));                     // bin 64
  float psd64 = re64 * re64 * 0.0078125f;

  const float mult = (l == 0) ? 1.f : 2.f;
  float psum = wsum(psd * mult) + psd64;
  float p2   = wsum(psd * psd * mult) + psd64 * psd64;
  float vm   = wmax(psd);
  float maxp = fmaxf(vm, psd64);
  float meanfreq = (-0.5f * psd64) / psum;
  float pbw = sqrtf(p2 / psum);
  float cand = (psd == vm) ? (float)l : 1e9f;              // first-index argmax
  float lminf = wmin(cand);
  float fmaxv = (psd64 > vm) ? -0.5f : lminf * (1.0f / 128.0f);
  float maxamp = sqrtf(maxp * 128.0f);

  // ---- median (stable rank 64 of 128, multiplicity-aware ballot rank) ----
  float med = -0.5f;
  for (int kt = 0; kt < 64; ++kt){
    float vt = __int_as_float(__builtin_amdgcn_readlane(__float_as_int(psd), kt));
    unsigned long long mask = __ballot(psd < vt);
    int less = 2 * __popcll(mask) - (int)(mask & 1ull) + ((psd64 < vt) ? 1 : 0);
    if (less == 64) med = (float)kt * (1.0f / 128.0f);
    else if (less == 63 && kt >= 1) med = -(float)kt * (1.0f / 128.0f);
  }
  {
    unsigned long long mask = __ballot(psd < psd64);
    int less = 2 * __popcll(mask) - (int)(mask & 1ull);
    if (less == 64) med = -0.5f;
  }

  if (l == 0){
    float* o = Xf + (size_t)pp * 40;
    o[0]  = mx;  o[1]  = mn;  o[2]  = sd;   o[3]  = rms; o[4]  = mean;
    o[5]  = mx - mn;  o[6] = var;  o[7] = ent; o[8] = std_asin; o[9] = std_atan;
    o[10] = kurt; o[11] = skew;
    o[12] = meanfreq;
    o[13] = med;
    o[14] = psum;
    o[15] = 1.0f;
    o[16] = pbw;
    o[17] = maxp;
    o[18] = maxamp;
    o[19] = fmaxv;
  }
}

// ---------- K2: cumsum feature + per-sample normalization ----------
__global__ __launch_bounds__(256) void cumnorm_kernel(float* __restrict__ Xf){
  const int b = blockIdx.x, t = threadIdx.x;
  __shared__ float arr[128 * 40];
  __shared__ float red4[4];
  float* base = Xf + b * 5120;
  for (int idx = t; idx < 128 * 20; idx += 256){
    int p = idx / 20, c = idx - p * 20;
    arr[p * 40 + c] = base[p * 40 + c];
  }
  __syncthreads();
  if (t < 20){
    float acc = 0.f;
    for (int p = 0; p < 128; ++p){
      acc += arr[p * 40 + t];
      arr[p * 40 + 20 + t] = acc / sqrtf(fmaxf(fabsf(acc), 1e-12f));
    }
  }
  __syncthreads();
  float pa = 0.f;
  for (int idx = t; idx < 5120; idx += 256){ float v = arr[idx]; pa = fmaf(v, v, pa); }
  float nrm = sqrtf(rsum256(pa, red4));
  for (int idx = t; idx < 5120; idx += 256) base[idx] = arr[idx] / nrm;
}

// ---------- K3: A_t (register-tiled fp32) ----------
__global__ __launch_bounds__(256) void adjt_kernel(const float* __restrict__ Xf,
    const float* __restrict__ w1, const float* __restrict__ b1,
    const float* __restrict__ w2, const float* __restrict__ b2,
    float* __restrict__ At){
  const int b = blockIdx.x, t = threadIdx.x;
  __shared__ float xf[5120];          // stride 40
  __shared__ float T[128 * 64];
  const float* src = Xf + b * 5120;
  for (int idx = t; idx < 1280; idx += 256)
    *((float4*)xf + idx) = *((const float4*)src + idx);
  __syncthreads();
  {
    const int k0 = (t & 15) * 4, i0 = (t >> 4) * 8;
    float4 bv = *(const float4*)&b1[k0];
    float acc[8][4];
    #pragma unroll
    for (int di = 0; di < 8; ++di){ acc[di][0]=bv.x; acc[di][1]=bv.y; acc[di][2]=bv.z; acc[di][3]=bv.w; }
    for (int c = 0; c < 40; ++c){
      float4 wv = *(const float4*)&w1[c * 64 + k0];
      #pragma unroll
      for (int di = 0; di < 8; ++di){
        float xv = xf[(i0 + di) * 40 + c];
        acc[di][0] = fmaf(xv, wv.x, acc[di][0]);
        acc[di][1] = fmaf(xv, wv.y, acc[di][1]);
        acc[di][2] = fmaf(xv, wv.z, acc[di][2]);
        acc[di][3] = fmaf(xv, wv.w, acc[di][3]);
      }
    }
    #pragma unroll
    for (int di = 0; di < 8; ++di){
      float4 o;
      o.x = tanhf(acc[di][0]); o.y = tanhf(acc[di][1]);
      o.z = tanhf(acc[di][2]); o.w = tanhf(acc[di][3]);
      *(float4*)&T[(i0 + di) * 64 + k0] = o;
    }
  }
  __syncthreads();
  {
    const int j0 = (t & 31) * 4, i0 = (t >> 5) * 16;
    float4 bv = *(const float4*)&b2[j0];
    float acc[16][4];
    #pragma unroll
    for (int di = 0; di < 16; ++di){ acc[di][0]=bv.x; acc[di][1]=bv.y; acc[di][2]=bv.z; acc[di][3]=bv.w; }
    for (int k = 0; k < 64; ++k){
      float4 wv = *(const float4*)&w2[k * 128 + j0];
      #pragma unroll
      for (int di = 0; di < 16; ++di){
        float tv = T[(i0 + di) * 64 + k];
        acc[di][0] = fmaf(tv, wv.x, acc[di][0]);
        acc[di][1] = fmaf(tv, wv.y, acc[di][1]);
        acc[di][2] = fmaf(tv, wv.z, acc[di][2]);
        acc[di][3] = fmaf(tv, wv.w, acc[di][3]);
      }
    }
    float* dst = At + (size_t)b * 16384;
    #pragma unroll
    for (int di = 0; di < 16; ++di)
      *(float4*)&dst[(i0 + di) * 128 + j0] = *(float4*)acc[di];
  }
}

// ---------- K4: A_s ----------
__global__ __launch_bounds__(256) void adjs_kernel(const float* __restrict__ Xf,
    const float* __restrict__ w1, const float* __restrict__ b1,
    const float* __restrict__ w2, const float* __restrict__ b2,
    float* __restrict__ As){
  const int b = blockIdx.x, t = threadIdx.x;
  __shared__ float xf[5120];
  __shared__ float T2[40 * 64];
  const float* src = Xf + b * 5120;
  for (int idx = t; idx < 1280; idx += 256)
    *((float4*)xf + idx) = *((const float4*)src + idx);
  __syncthreads();
  for (int idx = t; idx < 40 * 64; idx += 256){
    int i = idx >> 6, k = idx & 63;
    float acc = b1[k];
    for (int p = 0; p < 128; ++p) acc = fmaf(xf[p * 40 + i], w1[p * 64 + k], acc);
    T2[idx] = tanhf(acc);
  }
  __syncthreads();
  float* dst = As + b * 1600;
  for (int idx = t; idx < 1600; idx += 256){
    int i = idx / 40, j = idx - i * 40;
    float acc = b2[j];
    #pragma unroll 8
    for (int k = 0; k < 64; ++k) acc = fmaf(T2[i * 64 + k], w2[k * 40 + j], acc);
    dst[idx] = acc;
  }
}

// ---------- K5: H_s (register-tiled) ----------
__global__ __launch_bounds__(256) void hs_kernel(const float* __restrict__ Xf,
    const float* __restrict__ As_g, const float* __restrict__ w, const float* __restrict__ bias,
    float* __restrict__ H){
  const int b = blockIdx.x, t = threadIdx.x;
  __shared__ float xf[5120];          // stride 40
  __shared__ float As[1600];
  __shared__ float M[40 * 128];
  const float* src = Xf + b * 5120;
  for (int idx = t; idx < 1280; idx += 256)
    *((float4*)xf + idx) = *((const float4*)src + idx);
  for (int idx = t; idx < 400; idx += 256)
    *((float4*)As + idx) = *((const float4*)(As_g + b * 1600) + idx);
  __syncthreads();
  {
    const int p0 = (t & 31) * 4, i0 = (t >> 5) * 5;
    float acc[5][4];
    #pragma unroll
    for (int di = 0; di < 5; ++di)
      #pragma unroll
      for (int dp = 0; dp < 4; ++dp) acc[di][dp] = 0.f;
    for (int m = 0; m < 40; m += 4){
      float4 a4[5], x4[4];
      #pragma unroll
      for (int di = 0; di < 5; ++di) a4[di] = *(const float4*)&As[(i0 + di) * 40 + m];
      #pragma unroll
      for (int dp = 0; dp < 4; ++dp) x4[dp] = *(const float4*)&xf[(p0 + dp) * 40 + m];
      #pragma unroll
      for (int dm = 0; dm < 4; ++dm)
        #pragma unroll
        for (int di = 0; di < 5; ++di){
          float av = (&a4[di].x)[dm];
          #pragma unroll
          for (int dp = 0; dp < 4; ++dp)
            acc[di][dp] = fmaf(av, (&x4[dp].x)[dm], acc[di][dp]);
        }
    }
    #pragma unroll
    for (int di = 0; di < 5; ++di)
      *(float4*)&M[(i0 + di) * 128 + p0] = *(float4*)acc[di];
  }
  __syncthreads();
  {
    const int j0 = (t & 31) * 4, i0 = (t >> 5) * 5;
    float4 bv = *(const float4*)&bias[j0];
    float acc[5][4];
    #pragma unroll
    for (int di = 0; di < 5; ++di){ acc[di][0]=bv.x; acc[di][1]=bv.y; acc[di][2]=bv.z; acc[di][3]=bv.w; }
    for (int p = 0; p < 128; ++p){
      float4 wv = *(const float4*)&w[p * 128 + j0];
      #pragma unroll
      for (int di = 0; di < 5; ++di){
        float mv = M[(i0 + di) * 128 + p];
        acc[di][0] = fmaf(mv, wv.x, acc[di][0]);
        acc[di][1] = fmaf(mv, wv.y, acc[di][1]);
        acc[di][2] = fmaf(mv, wv.z, acc[di][2]);
        acc[di][3] = fmaf(mv, wv.w, acc[di][3]);
      }
    }
    float* dst = H + (size_t)b * (N * HG);
    #pragma unroll
    for (int di = 0; di < 5; ++di){
      float4 o;
      o.x = (acc[di][0] >= 0.f) ? acc[di][0] : 0.01f * acc[di][0];
      o.y = (acc[di][1] >= 0.f) ? acc[di][1] : 0.01f * acc[di][1];
      o.z = (acc[di][2] >= 0.f) ? acc[di][2] : 0.01f * acc[di][2];
      o.w = (acc[di][3] >= 0.f) ? acc[di][3] : 0.01f * acc[di][3];
      *(float4*)&dst[(i0 + di) * 128 + j0] = o;
    }
  }
}

// ---------- K6: H_t (register-tiled) ----------
__global__ __launch_bounds__(256) void ht_kernel(const float* __restrict__ Xf,
    const float* __restrict__ At_g, const float* __restrict__ w, const float* __restrict__ bias,
    float* __restrict__ H){
  const int b = blockIdx.x, t = threadIdx.x;
  __shared__ float xf[5120];          // stride 40
  __shared__ float M2[128 * 40];
  const float* src = Xf + b * 5120;
  for (int idx = t; idx < 1280; idx += 256)
    *((float4*)xf + idx) = *((const float4*)src + idx);
  __syncthreads();
  {
    const int c0 = (t & 7) * 5, i0 = (t >> 3) * 4;
    const float* At = At_g + (size_t)b * 16384;
    float acc[4][5];
    #pragma unroll
    for (int di = 0; di < 4; ++di)
      #pragma unroll
      for (int dc = 0; dc < 5; ++dc) acc[di][dc] = 0.f;
    for (int m = 0; m < 128; m += 4){
      float4 a4[4];
      #pragma unroll
      for (int di = 0; di < 4; ++di) a4[di] = *(const float4*)&At[(i0 + di) * 128 + m];
      #pragma unroll
      for (int dm = 0; dm < 4; ++dm){
        float xv[5];
        #pragma unroll
        for (int dc = 0; dc < 5; ++dc) xv[dc] = xf[(m + dm) * 40 + c0 + dc];
        #pragma unroll
        for (int di = 0; di < 4; ++di){
          float av = (&a4[di].x)[dm];
          #pragma unroll
          for (int dc = 0; dc < 5; ++dc)
            acc[di][dc] = fmaf(av, xv[dc], acc[di][dc]);
        }
      }
    }
    #pragma unroll
    for (int di = 0; di < 4; ++di)
      #pragma unroll
      for (int dc = 0; dc < 5; ++dc)
        M2[(i0 + di) * 40 + c0 + dc] = acc[di][dc];
  }
  __syncthreads();
  {
    const int j0 = (t & 31) * 4, i0 = (t >> 5) * 16;
    float4 bv = *(const float4*)&bias[j0];
    float acc[16][4];
    #pragma unroll
    for (int di = 0; di < 16; ++di){ acc[di][0]=bv.x; acc[di][1]=bv.y; acc[di][2]=bv.z; acc[di][3]=bv.w; }
    for (int c = 0; c < 40; ++c){
      float4 wv = *(const float4*)&w[c * 128 + j0];
      #pragma unroll
      for (int di = 0; di < 16; ++di){
        float mv = M2[(i0 + di) * 40 + c];
        acc[di][0] = fmaf(mv, wv.x, acc[di][0]);
        acc[di][1] = fmaf(mv, wv.y, acc[di][1]);
        acc[di][2] = fmaf(mv, wv.z, acc[di][2]);
        acc[di][3] = fmaf(mv, wv.w, acc[di][3]);
      }
    }
    float* dst = H + (size_t)b * (N * HG) + 40 * 128;
    #pragma unroll
    for (int di = 0; di < 16; ++di){
      float4 o;
      o.x = (acc[di][0] >= 0.f) ? acc[di][0] : 0.01f * acc[di][0];
      o.y = (acc[di][1] >= 0.f) ? acc[di][1] : 0.01f * acc[di][1];
      o.z = (acc[di][2] >= 0.f) ? acc[di][2] : 0.01f * acc[di][2];
      o.w = (acc[di][3] >= 0.f) ? acc[di][3] : 0.01f * acc[di][3];
      *(float4*)&dst[(i0 + di) * 128 + j0] = o;
    }
  }
}

// ---------- init out: fc_b + sum(vb x fcw) folded constant (softmax rows sum to 1) ----------
__global__ __launch_bounds__(256) void initout_kernel(float* __restrict__ out,
    const float* __restrict__ fcb, const float* __restrict__ fcw,
    const float* __restrict__ vb){
  __shared__ float red4[4];
  float p = 0.f;
  for (int k = threadIdx.x; k < 86016; k += 256)
    p = fmaf(fcw[k], vb[k & 511], p);
  float tot = rsum256(p, red4);
  float v = fcb[0] + tot;
  for (int i = threadIdx.x; i < BSZ; i += 256) out[i] = v;
}

// ---------- fcw -> bf16, head-major: fcwb[h][n][e] ----------
__global__ __launch_bounds__(256) void fcwcast_kernel(const float* __restrict__ fcw,
                                                      short* __restrict__ fcwb){
  int idx = blockIdx.x * 256 + threadIdx.x;
  if (idx < 86016){
    int n = idx >> 9, h = (idx >> 7) & 3, e = idx & 127;
    fcwb[((h * 168) + n) * 128 + e] = (short)f2bf(fcw[idx]);
  }
}

// ---------- prep: per-head M^T, Wv^T, c1/c2/c3; sliced over 8 blocks/head ----------
__global__ __launch_bounds__(256) void prep_kernel(
    const float* __restrict__ qw, const float* __restrict__ qb,
    const float* __restrict__ kw, const float* __restrict__ kb,
    const float* __restrict__ vw,
    short* __restrict__ MT, short* __restrict__ WvT,
    float* __restrict__ c1, float* __restrict__ c2, float* __restrict__ c3){
  const int h = blockIdx.x, sl = blockIdx.y, t = threadIdx.x;
  const float* Q = qw + h * 16384;
  const float* K = kw + h * 16384;
  const float* V = vw + h * 16384;
  for (int idx = t; idx < 2048; idx += 256){
    int j = sl * 16 + (idx >> 7), d = idx & 127;
    float acc = 0.f;
    for (int e = 0; e < 128; ++e) acc = fmaf(Q[d * 128 + e], K[j * 128 + e], acc);
    MT[h * 16384 + j * 128 + d] = (short)f2bf(acc);     // MT[j][d] = M[d][j]
  }
  for (int idx = t; idx < 2048; idx += 256){
    int e = sl * 16 + (idx >> 7), d = idx & 127;
    WvT[h * 16384 + e * 128 + d] = (short)f2bf(V[d * 128 + e]);
  }
  if (t < 16){
    int r = sl * 16 + t;
    float a = 0.f, bsum = 0.f;
    for (int e = 0; e < 128; ++e){
      a    = fmaf(Q[r * 128 + e], kb[h * 128 + e], a);
      bsum = fmaf(K[r * 128 + e], qb[h * 128 + e], bsum);
    }
    c1[h * 128 + r] = a;
    c2[h * 128 + r] = bsum;
  }
  if (t == 16 && sl == 0){
    float a = 0.f;
    for (int e = 0; e < 128; ++e) a = fmaf(qb[h * 128 + e], kb[h * 128 + e], a);
    c3[h] = a;
  }
}

// ---------- cast H -> bf16 with zero-padded rows 168..175 ----------
__global__ __launch_bounds__(256) void cast_kernel(const float* __restrict__ H,
                                                   short* __restrict__ Hbf){
  const int b = blockIdx.x;
  for (int idx = threadIdx.x; idx < NPAD * 128; idx += 256){
    int n = idx >> 7, d = idx & 127;
    float v = (n < N) ? H[((size_t)b * N + n) * 128 + d] : 0.f;
    Hbf[(size_t)b * NPAD * 128 + idx] = (short)f2bf(v);
  }
}

// ---------- u1/u2 precompute: u1[n]=H[n]·c1, u2[n]=H[n]·c2 per (b,h) ----------
__global__ __launch_bounds__(256) void uprep_kernel(const short* __restrict__ Hbf,
    const float* __restrict__ c1, const float* __restrict__ c2,
    float* __restrict__ u1g, float* __restrict__ u2g){
  const int b = blockIdx.x, t = threadIdx.x;
  for (int idx = t; idx < 176 * 4; idx += 256){
    int n = idx >> 2, h = idx & 3;
    const bf16x8* rp = (const bf16x8*)(Hbf + (size_t)b * NPAD * 128 + (size_t)n * 128);
    const float* C1 = c1 + h * 128;
    const float* C2 = c2 + h * 128;
    float a1 = 0.f, a2 = 0.f;
    for (int kk = 0; kk < 16; ++kk){
      bf16x8 v = rp[kk];
      #pragma unroll
      for (int j = 0; j < 8; ++j){
        float hv = bf2f((unsigned short)v[j]);
        a1 = fmaf(hv, C1[kk * 8 + j], a1);
        a2 = fmaf(hv, C2[kk * 8 + j], a2);
      }
    }
    u1g[(size_t)(b * 4 + h) * 176 + n] = a1;
    u2g[(size_t)(b * 4 + h) * 176 + n] = a2;
  }
}

// ---------- fused attention: XCD-swizzled 1-D grid; one block per (b,h) ----------
__global__ __launch_bounds__(256, 4) void attn_fused(
    const short* __restrict__ Hbf, const short* __restrict__ MT,
    const short* __restrict__ WvT,
    const float* __restrict__ u1g, const float* __restrict__ u2g,
    const float* __restrict__ c3g, const short* __restrict__ fcwb,
    float* __restrict__ out){
  const int id = blockIdx.x;
  const int xcd = id & 7, slot = id >> 3;
  const int b = xcd * 128 + (slot >> 2);
  const int h = slot & 3;
  const int t = threadIdx.x;
  const int w = t >> 6, l = t & 63, quad = l >> 4, l15 = l & 15;

  __shared__ __align__(16) short Tsh[48 * 128];     // T (XOR-swizzled), per z
  __shared__ __align__(16) short U[4 * 16 * 200];   // phase W scratch, then Ssh (48x184)
  __shared__ float u1f[176];
  __shared__ float u2f[176];
  __shared__ float red4[4];

  const short* Hb   = Hbf + (size_t)b * NPAD * 128;
  const short* MTh  = MT + h * 16384;
  const short* WvTh = WvT + h * 16384;
  const short* Fh   = fcwb + h * (168 * 128);
  const float c3v = c3g[h];
  const float inv = 0.08838834764831845f;   // 1/sqrt(128)

  if (t < 176){
    u1f[t] = u1g[(size_t)(b * 4 + h) * 176 + t];
    u2f[t] = u2g[(size_t)(b * 4 + h) * 176 + t];
  }

  // ---- Phase W: HWvT B-fragments -> registers (per-wave scratch, no barrier) ----
  // ei loops FULLY UNROLLED so W2f stays register-resident (r8: runtime ei
  // indexing pushed W2f to scratch -> 200 MB HBM writes).
  bf16x8 W2f[2][6];
  {
    short* sc = &U[w * 3200];          // 16 x 200 per wave
    #pragma unroll
    for (int ei = 0; ei < 2; ++ei){
      const int et = w * 2 + ei;
      bf16x8 A[4];
      #pragma unroll
      for (int kk = 0; kk < 4; ++kk)
        A[kk] = *(const bf16x8*)(WvTh + (size_t)(et * 16 + l15) * 128 + kk * 32 + quad * 8);
      for (int mt = 0; mt < 11; ++mt){
        f32x4 acc = {0.f, 0.f, 0.f, 0.f};
        #pragma unroll
        for (int kk = 0; kk < 4; ++kk){
          bf16x8 B = *(const bf16x8*)(Hb + (size_t)(mt * 16 + l15) * 128 + kk * 32 + quad * 8);
          acc = __builtin_amdgcn_mfma_f32_16x16x32_bf16(A[kk], B, acc, 0, 0, 0);
        }
        #pragma unroll
        for (int r = 0; r < 4; ++r)
          sc[(quad * 4 + r) * 200 + mt * 16 + l15] = (short)f2bf(acc[r]);
      }
      { // zero cols 176..191 (16 rows x 16 cols, one 8B write per lane)
        int row = l >> 2, co = 176 + (l & 3) * 4;
        *(unsigned long long*)(&sc[row * 200 + co]) = 0ull;
      }
      #pragma unroll
      for (int kt = 0; kt < 6; ++kt)
        W2f[ei][kt] = *(const bf16x8*)(&sc[l15 * 200 + kt * 32 + quad * 8]);
    }
  }
  __syncthreads();    // scratch dead; u1f/u2f visible

  float tp = 0.f;
  short* Ssh = U;     // 48 rows, stride 184
  for (int z = 0; z < 4; ++z){
    const int NT = (z < 3) ? 3 : 2;
    const int rowbase = z * 48;

    // ---- Phase A: T = H_rows @ M (write bf16, XOR-swizzled) ----
    for (int jt = 0; jt < 2; ++jt){
      const int j0 = (w * 2 + jt) * 16;
      bf16x8 B[4];
      #pragma unroll
      for (int kk = 0; kk < 4; ++kk)
        B[kk] = *(const bf16x8*)(MTh + (j0 + l15) * 128 + kk * 32 + quad * 8);
      for (int nt = 0; nt < NT; ++nt){
        f32x4 acc = {0.f, 0.f, 0.f, 0.f};
        #pragma unroll
        for (int kk = 0; kk < 4; ++kk){
          bf16x8 A = *(const bf16x8*)(Hb + (size_t)(rowbase + nt * 16 + l15) * 128 + kk * 32 + quad * 8);
          acc = __builtin_amdgcn_mfma_f32_16x16x32_bf16(A, B[kk], acc, 0, 0, 0);
        }
        const int jcol = j0 + l15, ch = jcol >> 3;
        #pragma unroll
        for (int r = 0; r < 4; ++r){
          int row = nt * 16 + quad * 4 + r;
          Tsh[row * 128 + ((ch ^ (row & 15)) << 3) + (jcol & 7)] = (short)f2bf(acc[r]);
        }
      }
    }
    __syncthreads();

    // ---- Phase S: S = T @ H^T (+rank-1 terms), bf16 into Ssh ----
    for (int mi = 0; mi < 3; ++mi){
      const int mt = w + mi * 4;
      if (mt >= 11) break;
      const int m0 = mt * 16;
      bf16x8 B[4];
      #pragma unroll
      for (int kk = 0; kk < 4; ++kk)
        B[kk] = *(const bf16x8*)(Hb + (size_t)(m0 + l15) * 128 + kk * 32 + quad * 8);
      const int m = m0 + l15;
      const float u2v = u2f[m];
      for (int nt = 0; nt < NT; ++nt){
        f32x4 acc = {0.f, 0.f, 0.f, 0.f};
        #pragma unroll
        for (int kk = 0; kk < 4; ++kk){
          int row = nt * 16 + l15;
          bf16x8 A = *(const bf16x8*)(&Tsh[row * 128 + (((kk * 4 + quad) ^ l15) << 3)]);
          acc = __builtin_amdgcn_mfma_f32_16x16x32_bf16(A, B[kk], acc, 0, 0, 0);
        }
        #pragma unroll
        for (int r = 0; r < 4; ++r){
          int nl = nt * 16 + quad * 4 + r;
          float s = (acc[r] + u1f[rowbase + nl] + u2v + c3v) * inv;
          Ssh[nl * 184 + m] = (short)f2bf(s);
        }
      }
    }
    __syncthreads();

    // ---- softmax: one row per wave pass; cols 0..167 valid, 168..183 -> 0 ----
    {
      const int nrw = NT * 4;
      for (int rr = 0; rr < nrw; ++rr){
        const int r = w * nrw + rr;
        short* rowp = &Ssh[r * 184];
        float v0 = bf2f((unsigned short)rowp[l]);
        float v1 = bf2f((unsigned short)rowp[64 + l]);
        float v2 = (l < 40) ? bf2f((unsigned short)rowp[128 + l]) : -1e30f;
        float mv = wmax(fmaxf(fmaxf(v0, v1), v2));
        float e0 = __expf(v0 - mv);
        float e1 = __expf(v1 - mv);
        float e2 = (l < 40) ? __expf(v2 - mv) : 0.f;
        float sinv = 1.f / wsum(e0 + e1 + e2);
        rowp[l]      = (short)f2bf(e0 * sinv);
        rowp[64 + l] = (short)f2bf(e1 * sinv);
        if (l < 56) rowp[128 + l] = (l < 40) ? (short)f2bf(e2 * sinv) : (short)0;
      }
    }
    __syncthreads();

    // ---- Phase O: O = P @ HWv (B from registers), fused FC (bf16 fcwb) ----
    #pragma unroll
    for (int ei = 0; ei < 2; ++ei){
      const int e0 = (w * 2 + ei) * 16;
      for (int nt = 0; nt < NT; ++nt){
        f32x4 acc = {0.f, 0.f, 0.f, 0.f};
        #pragma unroll
        for (int kt = 0; kt < 6; ++kt){
          bf16x8 A = {0, 0, 0, 0, 0, 0, 0, 0};
          if (kt != 5 || quad < 2)
            A = *(const bf16x8*)(&Ssh[(nt * 16 + l15) * 184 + kt * 32 + quad * 8]);
          acc = __builtin_amdgcn_mfma_f32_16x16x32_bf16(A, W2f[ei][kt], acc, 0, 0, 0);
        }
        #pragma unroll
        for (int r = 0; r < 4; ++r){
          int ng = rowbase + nt * 16 + quad * 4 + r;
          if (ng < N)
            tp = fmaf(acc[r], bf2f((unsigned short)Fh[ng * 128 + e0 + l15]), tp);
        }
      }
    }
    __syncthreads();   // protect Tsh/Ssh reuse next z
  }
  float tot = rsum256(tp, red4);
  if (t == 0) atomicAdd(out + b, tot);
}

} // anonymous namespace

extern "C" void kernel_launch(void* const* d_in, const int* in_sizes, int n_in,
                              void* d_out, int out_size, void* d_ws, size_t ws_size,
                              hipStream_t stream) {
  (void)in_sizes; (void)n_in; (void)out_size;
  const float* X      = (const float*)d_in[0];
  const float* spa_w1 = (const float*)d_in[1];
  const float* spa_b1 = (const float*)d_in[2];
  const float* spa_w2 = (const float*)d_in[3];
  const float* spa_b2 = (const float*)d_in[4];
  const float* tem_w1 = (const float*)d_in[5];
  const float* tem_b1 = (const float*)d_in[6];
  const float* tem_w2 = (const float*)d_in[7];
  const float* tem_b2 = (const float*)d_in[8];
  const float* sgnn_w = (const float*)d_in[9];
  const float* sgnn_b = (const float*)d_in[10];
  const float* tgnn_w = (const float*)d_in[11];
  const float* tgnn_b = (const float*)d_in[12];
  const float* q_w    = (const float*)d_in[13];
  const float* q_b    = (const float*)d_in[14];
  const float* k_w    = (const float*)d_in[15];
  const float* k_b    = (const float*)d_in[16];
  const float* v_w    = (const float*)d_in[17];
  const float* v_b    = (const float*)d_in[18];
  const float* fc_w   = (const float*)d_in[19];
  const float* fc_b   = (const float*)d_in[20];
  float* out = (float*)d_out;

  // ws layout (bytes):
  //   [0, 88,080,384): H fp32 (phase1) -> dead after cast
  //   Rb = 88,080,384:
  //       phase1: Xf (20,971,520) | As (6,553,600) | At (67,108,864; ends at ws end)
  //       phase2: Hbf bf16 1024x176x128 @ Rb (46,137,344)
  //               Pb = Rb+46,137,344 (dead At): MT|WvT|c1|c2|c3 (270,336)
  //               u1g/u2g @ Pb+270,336 (2x 2,883,584)
  //               fcwb bf16 4x168x128 @ Pb+6,037,504 (172,032)
  if (ws_size < (size_t)182714368) return;

  char* wsb = (char*)d_ws;
  float* H   = (float*)wsb;
  char*  Rb  = wsb + 88080384;
  float* Xf  = (float*)Rb;
  float* As  = (float*)(Rb + 20971520);
  float* At  = (float*)(Rb + 27525120);
  short* Hbf = (short*)Rb;
  char*  Pb  = Rb + 46137344;
  short* MT  = (short*)Pb;
  short* WvT = (short*)(Pb + 131072);
  float* c1  = (float*)(Pb + 262144);
  float* c2  = (float*)(Pb + 264192);
  float* c3  = (float*)(Pb + 266240);
  float* u1g = (float*)(Pb + 270336);
  float* u2g = (float*)(Pb + 270336 + 2883584);
  short* fcwb = (short*)(Pb + 6037504);

  feat_kernel<<<BSZ * P / 4, 256, 0, stream>>>(X, Xf);
  cumnorm_kernel<<<BSZ, 256, 0, stream>>>(Xf);
  adjt_kernel<<<BSZ, 256, 0, stream>>>(Xf, tem_w1, tem_b1, tem_w2, tem_b2, At);
  adjs_kernel<<<BSZ, 256, 0, stream>>>(Xf, spa_w1, spa_b1, spa_w2, spa_b2, As);
  hs_kernel<<<BSZ, 256, 0, stream>>>(Xf, As, sgnn_w, sgnn_b, H);
  ht_kernel<<<BSZ, 256, 0, stream>>>(Xf, At, tgnn_w, tgnn_b, H);
  prep_kernel<<<dim3(NH, 8), 256, 0, stream>>>(q_w, q_b, k_w, k_b, v_w, MT, WvT, c1, c2, c3);
  cast_kernel<<<BSZ, 256, 0, stream>>>(H, Hbf);          // H fp32 dead after this
  uprep_kernel<<<BSZ, 256, 0, stream>>>(Hbf, c1, c2, u1g, u2g);
  fcwcast_kernel<<<336, 256, 0, stream>>>(fc_w, fcwb);
  initout_kernel<<<1, 256, 0, stream>>>(out, fc_b, fc_w, v_b);
  attn_fused<<<NH * BSZ, 256, 0, stream>>>(Hbf, MT, WvT, u1g, u2g, c3, fcwb, out);
}